// Round 11
// baseline (73.275 us; speedup 1.0000x reference)
//
#include <hip/hip_runtime.h>

#define D 8
#define NE 4
#define NS 3
#define NI 5
#define LN_EPS 1e-5f

// weights-in-LDS float offsets (16B-aligned sections)
#define OFF_W1  0      // NS*64  = 192 (natural [s][d][k])
#define OFF_W2T 192    // NS*32  = 96  (transposed [s][d][e])
#define OFF_B1  288    // NS*8   = 24
#define OFF_B2  312    // NS*4   = 12
#define OFF_C   324    // NS*32  = 96  (n-paired [s][nn][d][2])
#define OFF_LN  420    // 16 (ln_g, ln_b)
#define OFF_WP  436    // NS*512 = 1536 (natural)
#define WLDS_SIZE 1972

typedef float f2 __attribute__((ext_vector_type(2)));

__device__ __forceinline__ f2 fma2(f2 a, f2 b, f2 c) { return __builtin_elementwise_fma(a, b, c); }
__device__ __forceinline__ f2 max2(f2 a, f2 b) { return __builtin_elementwise_max(a, b); }
__device__ __forceinline__ f2 bc(float s) { return (f2){s, s}; }

// lane <-> lane^1 exchange via DPP quad_perm [1,0,3,2]
__device__ __forceinline__ float xor1f(float x) {
    int i = __builtin_bit_cast(int, x);
    i = __builtin_amdgcn_mov_dpp(i, 0xB1, 0xF, 0xF, true);
    return __builtin_bit_cast(float, i);
}
__device__ __forceinline__ f2 xor1f2(f2 x) { return (f2){ xor1f(x.x), xor1f(x.y) }; }

__device__ __forceinline__ float4 ld4(const float* p) {
    return *reinterpret_cast<const float4*>(p);
}

// ---------------------------------------------------------------------------
// Setup kernel: C in n-PAIRED layout: C[s*32 + ((n>>1)*8 + d)*2 + (n&1)]
// ---------------------------------------------------------------------------
__global__ void precompute_C_kernel(const float* __restrict__ Bmat,
                                    const float* __restrict__ Wproj,
                                    const float* __restrict__ bproj,
                                    float* __restrict__ C) {
    int idx = threadIdx.x;
    if (idx >= NS * NE * D) return;
    int s = idx / (NE * D);
    int rem = idx % (NE * D);
    int n = rem / D;
    int d = rem % D;
    const float* bm = Bmat + ((size_t)s * NE + n) * 64;
    const float* wp = Wproj + ((size_t)s * D + d) * 64;
    float acc = bproj[s * D + d];
    #pragma unroll
    for (int k = 0; k < 64; ++k) acc += bm[k] * wp[k];
    C[s * 32 + ((n >> 1) * 8 + d) * 2 + (n & 1)] = acc;
}

__device__ __forceinline__ float fast_tanh(float x) {
    float e = __expf(2.f * x);
    return 1.f - 2.f * __builtin_amdgcn_rcpf(e + 1.f);
}

// ---------------------------------------------------------------------------
// Main kernel: TWO lanes per row (parity p owns d-half {4p..4p+3}) AND f2
// packing over expert pairs. 262144 threads -> 4 waves/SIMD physically;
// __launch_bounds__(256,2) keeps the backend's VGPR budget at 128 (declaring
// min=4 made it target 8 waves -> 64 regs -> spill; R7/R8 failure). Per-lane
// live set ~124: E2/H2 16+16, t 32 (REGISTERS — kills R10's 16 tbuf
// reads/iter), transients. LDS reads/iter: 16 broadcast (C 4, W1 8, W2T 4).
// Opaque-zero gates LICM of weight loads (R7-proven). DPP xor-1 cross-lane
// (R6/R7-proven correct).
// ---------------------------------------------------------------------------
__global__ __launch_bounds__(256, 2) void whisp_kernel(
    const float* __restrict__ cl, const float* __restrict__ cd,
    const float* __restrict__ re_log, const float* __restrict__ mach,
    const float* __restrict__ alpha, const float* __restrict__ u,
    const float* __restrict__ We, const float* __restrict__ be,
    const float* __restrict__ Wproj,
    const float* __restrict__ Wr1, const float* __restrict__ br1,
    const float* __restrict__ Wr2, const float* __restrict__ br2,
    const float* __restrict__ ln_g, const float* __restrict__ ln_b,
    const float* __restrict__ Wout, const float* __restrict__ bout,
    const float* __restrict__ fg, const float* __restrict__ fb,
    const float* __restrict__ Wcst, const float* __restrict__ bcst,
    const float* __restrict__ Wcl, const float* __restrict__ bcl,
    const float* __restrict__ Cpre,
    float* __restrict__ out, int B)
{
    __shared__ __align__(16) float wlds[WLDS_SIZE];   // 7888 B
    __shared__ float souts[128 * 19];                 // 9728 B

    const int tid = threadIdx.x;
    const int p   = tid & 1;
    const int rl  = tid >> 1;
    const int row0 = blockIdx.x * 128 + rl;
    const bool active = (row0 < B);
    const int row = active ? row0 : (B - 1);
    const int d0  = p * 4;
    const int d0o = d0 ^ 4;

    // ---- stage hot-loop weights into LDS ----
    for (int i = tid; i < 192;  i += 256) wlds[OFF_W1 + i] = Wr1[i];
    for (int i = tid; i < 96;   i += 256) {                       // W2 -> [s][d][e]
        int s = i / 32, rem = i % 32, d = rem / 4, e = rem % 4;
        wlds[OFF_W2T + i] = Wr2[s * 32 + e * 8 + d];
    }
    for (int i = tid; i < 24;   i += 256) wlds[OFF_B1 + i] = br1[i];
    for (int i = tid; i < 12;   i += 256) wlds[OFF_B2 + i] = br2[i];
    for (int i = tid; i < 96;   i += 256) wlds[OFF_C + i]  = Cpre[i];   // n-paired
    for (int i = tid; i < 8;    i += 256) { wlds[OFF_LN + i] = ln_g[i]; wlds[OFF_LN + 8 + i] = ln_b[i]; }
    for (int i = tid; i < 1536; i += 256) wlds[OFF_WP + i] = Wproj[i];

    // ---- per-row inputs ----
    float uu[8];
    {
        const float4* up = reinterpret_cast<const float4*>(u + (size_t)row * D);
        float4 u0 = up[0], u1 = up[1];
        uu[0]=u0.x; uu[1]=u0.y; uu[2]=u0.z; uu[3]=u0.w;
        uu[4]=u1.x; uu[5]=u1.y; uu[6]=u1.z; uu[7]=u1.w;
    }
    float xs[NE] = { cl[row], cd[row], re_log[row], mach[row] };
    float al = alpha[row];

    // ---- embedding: E2[nn][dd] = (E[2nn][d0+dd], E[2nn+1][d0+dd]) ----
    f2 E2[2][4];
    #pragma unroll
    for (int nn = 0; nn < 2; ++nn) {
        int na = 2 * nn, nb = 2 * nn + 1;
        float4 wa0 = ld4(We + na * 16 + d0 * 2), wa1 = ld4(We + na * 16 + d0 * 2 + 4);
        float4 wb0 = ld4(We + nb * 16 + d0 * 2), wb1 = ld4(We + nb * 16 + d0 * 2 + 4);
        float4 ba = ld4(be + na * D + d0), bb = ld4(be + nb * D + d0);
        E2[nn][0] = (f2){ fast_tanh(fmaf(wa0.x, xs[na], fmaf(wa0.y, al, ba.x))),
                          fast_tanh(fmaf(wb0.x, xs[nb], fmaf(wb0.y, al, bb.x))) };
        E2[nn][1] = (f2){ fast_tanh(fmaf(wa0.z, xs[na], fmaf(wa0.w, al, ba.y))),
                          fast_tanh(fmaf(wb0.z, xs[nb], fmaf(wb0.w, al, bb.y))) };
        E2[nn][2] = (f2){ fast_tanh(fmaf(wa1.x, xs[na], fmaf(wa1.y, al, ba.z))),
                          fast_tanh(fmaf(wb1.x, xs[nb], fmaf(wb1.y, al, bb.z))) };
        E2[nn][3] = (f2){ fast_tanh(fmaf(wa1.z, xs[na], fmaf(wa1.w, al, ba.w))),
                          fast_tanh(fmaf(wb1.z, xs[nb], fmaf(wb1.w, al, bb.w))) };
    }

    __syncthreads();   // wlds ready

    int zero = 0;      // opaque 0: blocks LICM of per-iteration weight loads

    // ---- outer stages ----
    #pragma unroll 1
    for (int s = 0; s < NS; ++s) {
        // t in REGISTERS: tA[dd][k]=t[d0+dd][d0+k], tB[dd][k]=t[d0+dd][d0o+k]
        float tA[4][4], tB[4][4];
        {
            const float* Wp = wlds + OFF_WP + s * 512;
            f2 uu2[4] = { {uu[0],uu[1]}, {uu[2],uu[3]}, {uu[4],uu[5]}, {uu[6],uu[7]} };
            #pragma unroll
            for (int dd = 0; dd < 4; ++dd) {
                #pragma unroll
                for (int k = 0; k < 4; ++k) {
                    const float* wA = Wp + (d0 + dd) * 64 + (d0 + k) * 8;
                    const float* wB = Wp + (d0 + dd) * 64 + (d0o + k) * 8;
                    float4 a0 = ld4(wA), a1 = ld4(wA + 4);
                    float4 b0 = ld4(wB), b1 = ld4(wB + 4);
                    f2 accA = uu2[0] * (f2){a0.x, a0.y};
                    accA = fma2(uu2[1], (f2){a0.z, a0.w}, accA);
                    accA = fma2(uu2[2], (f2){a1.x, a1.y}, accA);
                    accA = fma2(uu2[3], (f2){a1.z, a1.w}, accA);
                    tA[dd][k] = accA.x + accA.y;
                    f2 accB = uu2[0] * (f2){b0.x, b0.y};
                    accB = fma2(uu2[1], (f2){b0.z, b0.w}, accB);
                    accB = fma2(uu2[2], (f2){b1.x, b1.y}, accB);
                    accB = fma2(uu2[3], (f2){b1.z, b1.w}, accB);
                    tB[dd][k] = accB.x + accB.y;
                }
            }
        }

        // per-stage biases for my half
        float b1a[4], b2a[4];
        {
            float4 q = ld4(wlds + OFF_B1 + s * 8 + d0);
            b1a[0]=q.x; b1a[1]=q.y; b1a[2]=q.z; b1a[3]=q.w;
            float4 q2 = ld4(wlds + OFF_B2 + s * 4);
            b2a[0]=q2.x; b2a[1]=q2.y; b2a[2]=q2.z; b2a[3]=q2.w;
        }

        #pragma unroll 1
        for (int it = 0; it < NI; ++it) {
            asm volatile("" : "+v"(zero));
            const float* W1z  = wlds + OFF_W1  + s * 64 + zero;
            const float* W2Tz = wlds + OFF_W2T + s * 32 + zero;
            const float* Cz   = wlds + OFF_C   + s * 32 + zero;

            // exchange E halves (other lane's k-th element = col d0o+k)
            f2 Eo[2][4];
            #pragma unroll
            for (int nn = 0; nn < 2; ++nn)
                #pragma unroll
                for (int k = 0; k < 4; ++k) Eo[nn][k] = xor1f2(E2[nn][k]);

            // H2[nn][dd] = C + sum_k E2*tA + Eo*tB
            f2 H2[2][4];
            #pragma unroll
            for (int nn = 0; nn < 2; ++nn) {
                float4 c0 = ld4(Cz + nn * 16 + d0 * 2);       // (d0,d0+1) pairs
                float4 c1 = ld4(Cz + nn * 16 + d0 * 2 + 4);   // (d0+2,d0+3)
                H2[nn][0] = (f2){c0.x, c0.y};
                H2[nn][1] = (f2){c0.z, c0.w};
                H2[nn][2] = (f2){c1.x, c1.y};
                H2[nn][3] = (f2){c1.z, c1.w};
                #pragma unroll
                for (int dd = 0; dd < 4; ++dd) {
                    f2 acc = H2[nn][dd];
                    acc = fma2(E2[nn][0], bc(tA[dd][0]), acc);
                    acc = fma2(E2[nn][1], bc(tA[dd][1]), acc);
                    acc = fma2(E2[nn][2], bc(tA[dd][2]), acc);
                    acc = fma2(E2[nn][3], bc(tA[dd][3]), acc);
                    acc = fma2(Eo[nn][0], bc(tB[dd][0]), acc);
                    acc = fma2(Eo[nn][1], bc(tB[dd][1]), acc);
                    acc = fma2(Eo[nn][2], bc(tB[dd][2]), acc);
                    acc = fma2(Eo[nn][3], bc(tB[dd][3]), acc);
                    H2[nn][dd] = acc;
                }
            }

            // exchange H halves
            f2 Ho[2][4];
            #pragma unroll
            for (int nn = 0; nn < 2; ++nn)
                #pragma unroll
                for (int k = 0; k < 4; ++k) Ho[nn][k] = xor1f2(H2[nn][k]);

            // fused routing: r (my W1 rows) -> partial logits
            f2 lgp[2][NE];
            #pragma unroll
            for (int nn = 0; nn < 2; ++nn)
                #pragma unroll
                for (int e = 0; e < NE; ++e) lgp[nn][e] = bc(0.f);

            #pragma unroll
            for (int dd = 0; dd < 4; ++dd) {
                const float* w1r = W1z + (d0 + dd) * 8;
                float4 wa = ld4(w1r + d0);    // my-half k cols
                float4 wb = ld4(w1r + d0o);   // other-half k cols
                float4 w2 = ld4(W2Tz + (d0 + dd) * 4);
                #pragma unroll
                for (int nn = 0; nn < 2; ++nn) {
                    f2 acc = bc(b1a[dd]);
                    acc = fma2(H2[nn][0], bc(wa.x), acc);
                    acc = fma2(H2[nn][1], bc(wa.y), acc);
                    acc = fma2(H2[nn][2], bc(wa.z), acc);
                    acc = fma2(H2[nn][3], bc(wa.w), acc);
                    acc = fma2(Ho[nn][0], bc(wb.x), acc);
                    acc = fma2(Ho[nn][1], bc(wb.y), acc);
                    acc = fma2(Ho[nn][2], bc(wb.z), acc);
                    acc = fma2(Ho[nn][3], bc(wb.w), acc);
                    f2 r2 = max2(acc, bc(0.f));
                    lgp[nn][0] = fma2(r2, bc(w2.x), lgp[nn][0]);
                    lgp[nn][1] = fma2(r2, bc(w2.y), lgp[nn][1]);
                    lgp[nn][2] = fma2(r2, bc(w2.z), lgp[nn][2]);
                    lgp[nn][3] = fma2(r2, bc(w2.w), lgp[nn][3]);
                }
            }

            // cross-lane reduce + bias, then packed softmax over e
            f2 sm2[2][NE];
            #pragma unroll
            for (int nn = 0; nn < 2; ++nn) {
                f2 lg[NE];
                #pragma unroll
                for (int e = 0; e < NE; ++e)
                    lg[e] = lgp[nn][e] + xor1f2(lgp[nn][e]) + bc(b2a[e]);
                f2 m2 = max2(max2(lg[0], lg[1]), max2(lg[2], lg[3]));
                f2 ee[NE];
                #pragma unroll
                for (int e = 0; e < NE; ++e) {
                    f2 t = lg[e] - m2;
                    ee[e] = (f2){ __expf(t.x), __expf(t.y) };
                }
                f2 s2 = (ee[0] + ee[1]) + (ee[2] + ee[3]);
                f2 inv2 = (f2){ __builtin_amdgcn_rcpf(s2.x), __builtin_amdgcn_rcpf(s2.y) };
                #pragma unroll
                for (int e = 0; e < NE; ++e) sm2[nn][e] = ee[e] * inv2;
            }

            // E2[nn][dd] += sum_e sm2[nn][e] * H[e][dd]
            #pragma unroll
            for (int dd = 0; dd < 4; ++dd) {
                #pragma unroll
                for (int nn = 0; nn < 2; ++nn) {
                    f2 acc = E2[nn][dd];
                    acc = fma2(sm2[nn][0], bc(H2[0][dd].x), acc);
                    acc = fma2(sm2[nn][1], bc(H2[0][dd].y), acc);
                    acc = fma2(sm2[nn][2], bc(H2[1][dd].x), acc);
                    acc = fma2(sm2[nn][3], bc(H2[1][dd].y), acc);
                    E2[nn][dd] = acc;
                }
            }
        }

        // post-stage LayerNorm (cross-lane sums via DPP; params from LDS)
        float lngv[4], lnbv[4];
        {
            float4 g = ld4(wlds + OFF_LN + d0), b = ld4(wlds + OFF_LN + 8 + d0);
            lngv[0]=g.x; lngv[1]=g.y; lngv[2]=g.z; lngv[3]=g.w;
            lnbv[0]=b.x; lnbv[1]=b.y; lnbv[2]=b.z; lnbv[3]=b.w;
        }
        #pragma unroll
        for (int nn = 0; nn < 2; ++nn) {
            f2 sl = (E2[nn][0] + E2[nn][1]) + (E2[nn][2] + E2[nn][3]);
            f2 m2 = (sl + xor1f2(sl)) * bc(0.125f);
            f2 c[4];
            #pragma unroll
            for (int dd = 0; dd < 4; ++dd) c[dd] = E2[nn][dd] - m2;
            f2 v2 = fma2(c[0], c[0], c[1] * c[1]) + fma2(c[2], c[2], c[3] * c[3]);
            v2 = (v2 + xor1f2(v2)) * bc(0.125f);
            f2 inv2 = (f2){ __builtin_amdgcn_rsqf(v2.x + LN_EPS),
                            __builtin_amdgcn_rsqf(v2.y + LN_EPS) };
            #pragma unroll
            for (int dd = 0; dd < 4; ++dd)
                E2[nn][dd] = fma2(c[dd] * inv2, bc(lngv[dd]), bc(lnbv[dd]));
        }
    }

    // ---- final mixing: partial logits over my d-half, DPP-reduce ----
    float w0, w1, w2, w3;
    {
        float lgo[NE];
        #pragma unroll
        for (int e = 0; e < NE; ++e) {
            f2 acc2 = bc(0.f);
            #pragma unroll
            for (int nn = 0; nn < 2; ++nn) {
                #pragma unroll
                for (int dd = 0; dd < 4; ++dd) {
                    f2 wv = (f2){ Wout[e * 32 + (2 * nn) * D + d0 + dd],
                                  Wout[e * 32 + (2 * nn + 1) * D + d0 + dd] };
                    acc2 = fma2(E2[nn][dd], wv, acc2);
                }
            }
            float part = acc2.x + acc2.y;
            lgo[e] = part + xor1f(part) + bout[e];
        }
        float mx = fmaxf(fmaxf(lgo[0], lgo[1]), fmaxf(lgo[2], lgo[3]));
        w0 = __expf(lgo[0] - mx); w1 = __expf(lgo[1] - mx);
        w2 = __expf(lgo[2] - mx); w3 = __expf(lgo[3] - mx);
        float winv = __builtin_amdgcn_rcpf((w0 + w1) + (w2 + w3));
        w0 *= winv; w1 *= winv; w2 *= winv; w3 *= winv;
    }

    // z (my d-half) + final LN via DPP
    float z[4];
    #pragma unroll
    for (int dd = 0; dd < 4; ++dd) {
        float a0 = w0 * E2[0][dd].x;
        float a1 = w1 * E2[0][dd].y;
        a0 = fmaf(w2, E2[1][dd].x, a0);
        a1 = fmaf(w3, E2[1][dd].y, a1);
        z[dd] = a0 + a1;
    }
    {
        float sl = (z[0] + z[1]) + (z[2] + z[3]);
        float zm = (sl + xor1f(sl)) * 0.125f;
        float c0 = z[0] - zm, c1 = z[1] - zm, c2 = z[2] - zm, c3 = z[3] - zm;
        float vl = fmaf(c0, c0, c1 * c1) + fmaf(c2, c2, c3 * c3);
        float zv = (vl + xor1f(vl)) * 0.125f;
        float zinv = __builtin_amdgcn_rsqf(zv + LN_EPS);
        float4 g = ld4(fg + d0), b = ld4(fb + d0);
        z[0] = fmaf(c0 * zinv, g.x, b.x);
        z[1] = fmaf(c1 * zinv, g.y, b.y);
        z[2] = fmaf(c2 * zinv, g.z, b.z);
        z[3] = fmaf(c3 * zinv, g.w, b.w);
    }

    // heads: partial over my d-half, DPP-reduce, lane writes its k-parity
    #pragma unroll
    for (int k = 0; k < 18; ++k) {
        float4 wv = ld4(Wcst + k * D + d0);
        float a0 = z[0] * wv.x;
        float a1 = z[1] * wv.y;
        a0 = fmaf(z[2], wv.z, a0);
        a1 = fmaf(z[3], wv.w, a1);
        float part = a0 + a1;
        float full = part + xor1f(part) + bcst[k];
        if (active && ((k & 1) == p)) souts[rl * 19 + k] = full;
    }
    {
        float4 wv = ld4(Wcl + d0);
        float a0 = z[0] * wv.x;
        float a1 = z[1] * wv.y;
        a0 = fmaf(z[2], wv.z, a0);
        a1 = fmaf(z[3], wv.w, a1);
        float part = a0 + a1;
        float full = part + xor1f(part) + bcl[0];
        if (active && (p == 0)) souts[rl * 19 + 18] = full;
    }

    __syncthreads();

    // coalesced writeback of this block's 128x19 outputs
    const int base = blockIdx.x * 128;
    int nrows = B - base;
    if (nrows > 128) nrows = 128;
    if (nrows > 0) {
        const int cnt = nrows * 19;
        for (int i = tid; i < cnt; i += 256)
            out[(size_t)base * 19 + i] = souts[i];
    }
}

extern "C" void kernel_launch(void* const* d_in, const int* in_sizes, int n_in,
                              void* d_out, int out_size, void* d_ws, size_t ws_size,
                              hipStream_t stream) {
    const float* cl     = (const float*)d_in[0];
    const float* cd     = (const float*)d_in[1];
    const float* re_log = (const float*)d_in[2];
    const float* mach   = (const float*)d_in[3];
    const float* alpha  = (const float*)d_in[4];
    const float* u      = (const float*)d_in[5];
    const float* We     = (const float*)d_in[6];
    const float* be     = (const float*)d_in[7];
    const float* Bmat   = (const float*)d_in[8];
    const float* Wproj  = (const float*)d_in[9];
    const float* bproj  = (const float*)d_in[10];
    const float* Wr1    = (const float*)d_in[11];
    const float* br1    = (const float*)d_in[12];
    const float* Wr2    = (const float*)d_in[13];
    const float* br2    = (const float*)d_in[14];
    const float* ln_g   = (const float*)d_in[15];
    const float* ln_b   = (const float*)d_in[16];
    const float* Wout   = (const float*)d_in[17];
    const float* bout   = (const float*)d_in[18];
    const float* fg     = (const float*)d_in[19];
    const float* fb     = (const float*)d_in[20];
    const float* Wcst   = (const float*)d_in[21];
    const float* bcst   = (const float*)d_in[22];
    const float* Wcl    = (const float*)d_in[23];
    const float* bcl    = (const float*)d_in[24];

    float* Cpre = (float*)d_ws;   // 96 floats (n-paired layout)
    const int B = in_sizes[0];

    hipLaunchKernelGGL(precompute_C_kernel, dim3(1), dim3(128), 0, stream,
                       Bmat, Wproj, bproj, Cpre);

    const int blocks = (B + 127) / 128;   // 128 rows per 256-thread block
    hipLaunchKernelGGL(whisp_kernel, dim3(blocks), dim3(256), 0, stream,
                       cl, cd, re_log, mach, alpha, u, We, be, Wproj,
                       Wr1, br1, Wr2, br2, ln_g, ln_b, Wout, bout, fg, fb,
                       Wcst, bcst, Wcl, bcl, Cpre, (float*)d_out, B);
}

// Round 14
// 62.288 us; speedup vs baseline: 1.1764x; 1.1764x over previous
//
#include <hip/hip_runtime.h>

#define D 8
#define NE 4
#define NS 3
#define NI 5
#define LN_EPS 1e-5f

// weights-in-LDS float offsets (16B-aligned sections)
#define OFF_W1  0      // NS*64  = 192 (natural [s][d][k])
#define OFF_W2T 192    // NS*32  = 96  (transposed [s][d][e])
#define OFF_B1  288    // NS*8   = 24
#define OFF_B2  312    // NS*4   = 12
#define OFF_C   324    // NS*32  = 96  (n-paired [s][nn][d][2])
#define OFF_LN  420    // 16 (ln_g, ln_b)
#define OFF_WP  436    // NS*512 = 1536 (natural)
#define WLDS_SIZE 1972

typedef float f2 __attribute__((ext_vector_type(2)));

__device__ __forceinline__ f2 fma2(f2 a, f2 b, f2 c) { return __builtin_elementwise_fma(a, b, c); }
__device__ __forceinline__ f2 max2(f2 a, f2 b) { return __builtin_elementwise_max(a, b); }
__device__ __forceinline__ f2 bc(float s) { return (f2){s, s}; }

// ---------------------------------------------------------------------------
// Setup kernel: C in n-PAIRED layout: C[s*32 + ((n>>1)*8 + d)*2 + (n&1)]
// ---------------------------------------------------------------------------
__global__ void precompute_C_kernel(const float* __restrict__ Bmat,
                                    const float* __restrict__ Wproj,
                                    const float* __restrict__ bproj,
                                    float* __restrict__ C) {
    int idx = threadIdx.x;
    if (idx >= NS * NE * D) return;
    int s = idx / (NE * D);
    int rem = idx % (NE * D);
    int n = rem / D;
    int d = rem % D;
    const float* bm = Bmat + ((size_t)s * NE + n) * 64;
    const float* wp = Wproj + ((size_t)s * D + d) * 64;
    float acc = bproj[s * D + d];
    #pragma unroll
    for (int k = 0; k < 64; ++k) acc += bm[k] * wp[k];
    C[s * 32 + ((n >> 1) * 8 + d) * 2 + (n & 1)] = acc;
}

__device__ __forceinline__ float fast_tanh(float x) {
    float e = __expf(2.f * x);
    return 1.f - 2.f * __builtin_amdgcn_rcpf(e + 1.f);
}

__device__ __forceinline__ float4 ld4(const float* p) {
    return *reinterpret_cast<const float4*>(p);
}

// ---------------------------------------------------------------------------
// Main kernel: ONE thread per row, f2 packing over expert pairs (R10 shape —
// minimum issue volume). R14: t[8][8] lives in REGISTERS as exact f32 (f16
// failed correctness in R13: error compounds through the 15-iter recurrence).
// Register budget engineered <=128: uu lives in per-thread LDS (read back at
// each stage's t-compute only), biases re-read per iteration through gated
// addresses. Inner-loop LDS = 35 uniform-broadcast ld4 (C 8, W1 16, W2T 8,
// B 3) — the 16 per-lane full-bandwidth tbuf reads that throttled R10 are
// GONE. t is NOT gated (must stay live in regs); W1/W2/C/bias addresses keep
// the opaque-zero LICM gate (R7-proven; memory clobber would de-SROA, R6).
// ---------------------------------------------------------------------------
__global__ __launch_bounds__(256, 2) void whisp_kernel(
    const float* __restrict__ cl, const float* __restrict__ cd,
    const float* __restrict__ re_log, const float* __restrict__ mach,
    const float* __restrict__ alpha, const float* __restrict__ u,
    const float* __restrict__ We, const float* __restrict__ be,
    const float* __restrict__ Wproj,
    const float* __restrict__ Wr1, const float* __restrict__ br1,
    const float* __restrict__ Wr2, const float* __restrict__ br2,
    const float* __restrict__ ln_g, const float* __restrict__ ln_b,
    const float* __restrict__ Wout, const float* __restrict__ bout,
    const float* __restrict__ fg, const float* __restrict__ fb,
    const float* __restrict__ Wcst, const float* __restrict__ bcst,
    const float* __restrict__ Wcl, const float* __restrict__ bcl,
    const float* __restrict__ Cpre,
    float* __restrict__ out, int B)
{
    __shared__ __align__(16) float wlds[WLDS_SIZE];   // 7888 B
    __shared__ __align__(16) float4 ubuf[2 * 256];    // 8192 B (per-thread uu)
    __shared__ float souts[256 * 19];                 // 19456 B

    const int tid = threadIdx.x;
    const int row0 = blockIdx.x * 256 + tid;
    const bool active = (row0 < B);
    const int row = active ? row0 : (B - 1);

    // ---- stage hot-loop weights into LDS (once per block) ----
    for (int i = tid; i < 192;  i += 256) wlds[OFF_W1 + i] = Wr1[i];
    for (int i = tid; i < 96;   i += 256) {                       // W2 -> [s][d][e]
        int s = i / 32, rem = i % 32, d = rem / 4, e = rem % 4;
        wlds[OFF_W2T + i] = Wr2[s * 32 + e * 8 + d];
    }
    for (int i = tid; i < 24;   i += 256) wlds[OFF_B1 + i] = br1[i];
    for (int i = tid; i < 12;   i += 256) wlds[OFF_B2 + i] = br2[i];
    for (int i = tid; i < 96;   i += 256) wlds[OFF_C + i]  = Cpre[i];   // n-paired
    for (int i = tid; i < 8;    i += 256) { wlds[OFF_LN + i] = ln_g[i]; wlds[OFF_LN + 8 + i] = ln_b[i]; }
    for (int i = tid; i < 1536; i += 256) wlds[OFF_WP + i] = Wproj[i];

    // ---- per-row inputs; stash uu in per-thread LDS (frees 8 regs) ----
    {
        const float4* up = reinterpret_cast<const float4*>(u + (size_t)row * D);
        ubuf[tid]       = up[0];
        ubuf[256 + tid] = up[1];
    }
    float xs[NE] = { cl[row], cd[row], re_log[row], mach[row] };
    float al = alpha[row];

    // ---- embedding -> E2[nn][d] = (E[2nn][d], E[2nn+1][d]) ----
    f2 E2[2][D];
    #pragma unroll
    for (int nn = 0; nn < 2; ++nn) {
        #pragma unroll
        for (int d = 0; d < D; ++d) {
            int na = 2 * nn, nb = 2 * nn + 1;
            float pa = We[na * 16 + d * 2] * xs[na] + We[na * 16 + d * 2 + 1] * al + be[na * D + d];
            float pb = We[nb * 16 + d * 2] * xs[nb] + We[nb * 16 + d * 2 + 1] * al + be[nb * D + d];
            E2[nn][d] = (f2){ fast_tanh(pa), fast_tanh(pb) };
        }
    }

    __syncthreads();   // wlds + ubuf ready

    int zero = 0;      // opaque 0: blocks LICM of broadcast weight loads

    // ---- outer stages ----
    #pragma unroll 1
    for (int s = 0; s < NS; ++s) {
        // t[d][i] = sum_j u[j]*Wp[d][i*8+j] -> REGISTERS (f32, exact).
        // uu read back from per-thread LDS (transient; not live in loop).
        float t[D][D];
        {
            float4 uq0 = ubuf[tid], uq1 = ubuf[256 + tid];
            f2 uu2[4] = { {uq0.x,uq0.y}, {uq0.z,uq0.w}, {uq1.x,uq1.y}, {uq1.z,uq1.w} };
            const float* Wp = wlds + OFF_WP + s * 512;
            #pragma unroll
            for (int d = 0; d < D; ++d) {
                #pragma unroll
                for (int i = 0; i < D; ++i) {
                    float4 wa = ld4(Wp + d * 64 + i * 8);
                    float4 wb = ld4(Wp + d * 64 + i * 8 + 4);
                    f2 acc = uu2[0] * (f2){wa.x, wa.y};
                    acc = fma2(uu2[1], (f2){wa.z, wa.w}, acc);
                    acc = fma2(uu2[2], (f2){wb.x, wb.y}, acc);
                    acc = fma2(uu2[3], (f2){wb.z, wb.w}, acc);
                    t[d][i] = acc.x + acc.y;
                }
            }
        }

        #pragma unroll 1
        for (int it = 0; it < NI; ++it) {
            // gate broadcast weight addresses (t stays ungated, live in regs)
            asm volatile("" : "+v"(zero));
            const float* W1z  = wlds + OFF_W1  + s * 64 + zero;
            const float* W2Tz = wlds + OFF_W2T + s * 32 + zero;
            const float* Cz   = wlds + OFF_C   + s * 32 + zero;
            const float* B1z  = wlds + OFF_B1  + s * 8  + zero;
            const float* B2z  = wlds + OFF_B2  + s * 4  + zero;

            // H init from n-paired C (broadcast)
            f2 H2[2][D];
            #pragma unroll
            for (int nn = 0; nn < 2; ++nn) {
                #pragma unroll
                for (int dp = 0; dp < 4; ++dp) {
                    float4 cq = ld4(Cz + nn * 16 + dp * 4);
                    H2[nn][2 * dp]     = (f2){cq.x, cq.y};
                    H2[nn][2 * dp + 1] = (f2){cq.z, cq.w};
                }
            }
            // H2[nn][d] += sum_i E2[nn][i] * t[d][i]  (t from registers)
            #pragma unroll
            for (int d = 0; d < D; ++d) {
                #pragma unroll
                for (int nn = 0; nn < 2; ++nn) {
                    f2 acc = H2[nn][d];
                    acc = fma2(E2[nn][0], bc(t[d][0]), acc);
                    acc = fma2(E2[nn][1], bc(t[d][1]), acc);
                    acc = fma2(E2[nn][2], bc(t[d][2]), acc);
                    acc = fma2(E2[nn][3], bc(t[d][3]), acc);
                    acc = fma2(E2[nn][4], bc(t[d][4]), acc);
                    acc = fma2(E2[nn][5], bc(t[d][5]), acc);
                    acc = fma2(E2[nn][6], bc(t[d][6]), acc);
                    acc = fma2(E2[nn][7], bc(t[d][7]), acc);
                    H2[nn][d] = acc;
                }
            }

            // per-iteration biases (transient; gated -> not hoisted)
            float b1a[8], b2a[4];
            {
                float4 q0 = ld4(B1z);
                float4 q1 = ld4(B1z + 4);
                b1a[0]=q0.x; b1a[1]=q0.y; b1a[2]=q0.z; b1a[3]=q0.w;
                b1a[4]=q1.x; b1a[5]=q1.y; b1a[6]=q1.z; b1a[7]=q1.w;
                float4 q2 = ld4(B2z);
                b2a[0]=q2.x; b2a[1]=q2.y; b2a[2]=q2.z; b2a[3]=q2.w;
            }

            // fused routing: per d compute r2 then accumulate into lg
            f2 lg2[2][NE];
            #pragma unroll
            for (int nn = 0; nn < 2; ++nn)
                #pragma unroll
                for (int e = 0; e < NE; ++e) lg2[nn][e] = bc(b2a[e]);

            #pragma unroll
            for (int d = 0; d < D; ++d) {
                float4 wa = ld4(W1z + d * 8);
                float4 wb = ld4(W1z + d * 8 + 4);
                float4 w2 = ld4(W2Tz + d * 4);
                #pragma unroll
                for (int nn = 0; nn < 2; ++nn) {
                    f2 acc = bc(b1a[d]);
                    acc = fma2(H2[nn][0], bc(wa.x), acc);
                    acc = fma2(H2[nn][1], bc(wa.y), acc);
                    acc = fma2(H2[nn][2], bc(wa.z), acc);
                    acc = fma2(H2[nn][3], bc(wa.w), acc);
                    acc = fma2(H2[nn][4], bc(wb.x), acc);
                    acc = fma2(H2[nn][5], bc(wb.y), acc);
                    acc = fma2(H2[nn][6], bc(wb.z), acc);
                    acc = fma2(H2[nn][7], bc(wb.w), acc);
                    f2 r2 = max2(acc, bc(0.f));
                    lg2[nn][0] = fma2(r2, bc(w2.x), lg2[nn][0]);
                    lg2[nn][1] = fma2(r2, bc(w2.y), lg2[nn][1]);
                    lg2[nn][2] = fma2(r2, bc(w2.z), lg2[nn][2]);
                    lg2[nn][3] = fma2(r2, bc(w2.w), lg2[nn][3]);
                }
            }

            // packed softmax over e (per n; n's in f2 lanes)
            f2 sm2[2][NE];
            #pragma unroll
            for (int nn = 0; nn < 2; ++nn) {
                f2 m2 = max2(max2(lg2[nn][0], lg2[nn][1]), max2(lg2[nn][2], lg2[nn][3]));
                f2 ee[NE];
                #pragma unroll
                for (int e = 0; e < NE; ++e) {
                    f2 tt = lg2[nn][e] - m2;
                    ee[e] = (f2){ __expf(tt.x), __expf(tt.y) };
                }
                f2 s2 = (ee[0] + ee[1]) + (ee[2] + ee[3]);
                f2 inv2 = (f2){ __builtin_amdgcn_rcpf(s2.x), __builtin_amdgcn_rcpf(s2.y) };
                #pragma unroll
                for (int e = 0; e < NE; ++e) sm2[nn][e] = ee[e] * inv2;
            }

            // E2[nn][d] += sum_e sm2[nn][e] * H[e][d]
            #pragma unroll
            for (int d = 0; d < D; ++d) {
                #pragma unroll
                for (int nn = 0; nn < 2; ++nn) {
                    f2 acc = E2[nn][d];
                    acc = fma2(sm2[nn][0], bc(H2[0][d].x), acc);
                    acc = fma2(sm2[nn][1], bc(H2[0][d].y), acc);
                    acc = fma2(sm2[nn][2], bc(H2[1][d].x), acc);
                    acc = fma2(sm2[nn][3], bc(H2[1][d].y), acc);
                    E2[nn][d] = acc;
                }
            }
        }

        // post-stage LayerNorm (params from LDS; packed math)
        float lngv[8], lnbv[8];
        {
            float4 g0 = ld4(wlds + OFF_LN),     g1 = ld4(wlds + OFF_LN + 4);
            float4 b0 = ld4(wlds + OFF_LN + 8), b1 = ld4(wlds + OFF_LN + 12);
            lngv[0]=g0.x; lngv[1]=g0.y; lngv[2]=g0.z; lngv[3]=g0.w;
            lngv[4]=g1.x; lngv[5]=g1.y; lngv[6]=g1.z; lngv[7]=g1.w;
            lnbv[0]=b0.x; lnbv[1]=b0.y; lnbv[2]=b0.z; lnbv[3]=b0.w;
            lnbv[4]=b1.x; lnbv[5]=b1.y; lnbv[6]=b1.z; lnbv[7]=b1.w;
        }
        #pragma unroll
        for (int nn = 0; nn < 2; ++nn) {
            f2 s2 = (E2[nn][0] + E2[nn][1]) + (E2[nn][2] + E2[nn][3]);
            s2 = s2 + (E2[nn][4] + E2[nn][5]) + (E2[nn][6] + E2[nn][7]);
            f2 m2 = s2 * bc(0.125f);
            f2 v2 = bc(0.f);
            #pragma unroll
            for (int d = 0; d < D; ++d) { f2 c = E2[nn][d] - m2; v2 = fma2(c, c, v2); }
            v2 = v2 * bc(0.125f);
            f2 inv2 = (f2){ __builtin_amdgcn_rsqf(v2.x + LN_EPS),
                            __builtin_amdgcn_rsqf(v2.y + LN_EPS) };
            #pragma unroll
            for (int d = 0; d < D; ++d)
                E2[nn][d] = fma2((E2[nn][d] - m2) * inv2, bc(lngv[d]), bc(lnbv[d]));
        }
    }

    // ---- final mixing (one-time global weights; scalar epilogue) ----
    float lgf[NE];
    #pragma unroll
    for (int e = 0; e < NE; ++e) {
        float a0 = bout[e], a1 = 0.f;
        #pragma unroll
        for (int d = 0; d < D; ++d) {
            a0 = fmaf(E2[0][d].x, Wout[e * 32 + 0 * D + d], a0);
            a1 = fmaf(E2[0][d].y, Wout[e * 32 + 1 * D + d], a1);
            a0 = fmaf(E2[1][d].x, Wout[e * 32 + 2 * D + d], a0);
            a1 = fmaf(E2[1][d].y, Wout[e * 32 + 3 * D + d], a1);
        }
        lgf[e] = a0 + a1;
    }
    float mx = fmaxf(fmaxf(lgf[0], lgf[1]), fmaxf(lgf[2], lgf[3]));
    float w0 = __expf(lgf[0] - mx), w1 = __expf(lgf[1] - mx);
    float w2 = __expf(lgf[2] - mx), w3 = __expf(lgf[3] - mx);
    float winv = __builtin_amdgcn_rcpf((w0 + w1) + (w2 + w3));
    w0 *= winv; w1 *= winv; w2 *= winv; w3 *= winv;

    float z[D];
    #pragma unroll
    for (int d = 0; d < D; ++d) {
        float a0 = w0 * E2[0][d].x;
        float a1 = w1 * E2[0][d].y;
        a0 = fmaf(w2, E2[1][d].x, a0);
        a1 = fmaf(w3, E2[1][d].y, a1);
        z[d] = a0 + a1;
    }
    float zm = 0.f;
    #pragma unroll
    for (int d = 0; d < D; ++d) zm += z[d];
    zm *= (1.f / D);
    float zv = 0.f;
    #pragma unroll
    for (int d = 0; d < D; ++d) { float c = z[d] - zm; zv = fmaf(c, c, zv); }
    zv *= (1.f / D);
    float zinv = __builtin_amdgcn_rsqf(zv + LN_EPS);
    #pragma unroll
    for (int d = 0; d < D; ++d)
        z[d] = (z[d] - zm) * zinv * fg[d] + fb[d];

    // heads
    float zout[19];
    #pragma unroll
    for (int k = 0; k < 18; ++k) {
        float a0 = bcst[k], a1 = 0.f;
        #pragma unroll
        for (int d = 0; d < D; d += 2) {
            a0 = fmaf(z[d],     Wcst[k * D + d],     a0);
            a1 = fmaf(z[d + 1], Wcst[k * D + d + 1], a1);
        }
        zout[k] = a0 + a1;
    }
    {
        float a0 = bcl[0], a1 = 0.f;
        #pragma unroll
        for (int d = 0; d < D; d += 2) {
            a0 = fmaf(z[d],     Wcl[d],     a0);
            a1 = fmaf(z[d + 1], Wcl[d + 1], a1);
        }
        zout[18] = a0 + a1;
    }

    // stage via LDS for coalesced stores
    if (active) {
        #pragma unroll
        for (int k = 0; k < 19; ++k) souts[tid * 19 + k] = zout[k];
    }
    __syncthreads();

    const int base = blockIdx.x * 256;
    int nrows = B - base;
    if (nrows > 256) nrows = 256;
    if (nrows > 0) {
        const int cnt = nrows * 19;
        for (int i = tid; i < cnt; i += 256)
            out[(size_t)base * 19 + i] = souts[i];
    }
}

extern "C" void kernel_launch(void* const* d_in, const int* in_sizes, int n_in,
                              void* d_out, int out_size, void* d_ws, size_t ws_size,
                              hipStream_t stream) {
    const float* cl     = (const float*)d_in[0];
    const float* cd     = (const float*)d_in[1];
    const float* re_log = (const float*)d_in[2];
    const float* mach   = (const float*)d_in[3];
    const float* alpha  = (const float*)d_in[4];
    const float* u      = (const float*)d_in[5];
    const float* We     = (const float*)d_in[6];
    const float* be     = (const float*)d_in[7];
    const float* Bmat   = (const float*)d_in[8];
    const float* Wproj  = (const float*)d_in[9];
    const float* bproj  = (const float*)d_in[10];
    const float* Wr1    = (const float*)d_in[11];
    const float* br1    = (const float*)d_in[12];
    const float* Wr2    = (const float*)d_in[13];
    const float* br2    = (const float*)d_in[14];
    const float* ln_g   = (const float*)d_in[15];
    const float* ln_b   = (const float*)d_in[16];
    const float* Wout   = (const float*)d_in[17];
    const float* bout   = (const float*)d_in[18];
    const float* fg     = (const float*)d_in[19];
    const float* fb     = (const float*)d_in[20];
    const float* Wcst   = (const float*)d_in[21];
    const float* bcst   = (const float*)d_in[22];
    const float* Wcl    = (const float*)d_in[23];
    const float* bcl    = (const float*)d_in[24];

    float* Cpre = (float*)d_ws;   // 96 floats (n-paired layout)
    const int B = in_sizes[0];

    hipLaunchKernelGGL(precompute_C_kernel, dim3(1), dim3(128), 0, stream,
                       Bmat, Wproj, bproj, Cpre);

    const int blocks = (B + 255) / 256;
    hipLaunchKernelGGL(whisp_kernel, dim3(blocks), dim3(256), 0, stream,
                       cl, cd, re_log, mach, alpha, u, We, be, Wproj,
                       Wr1, br1, Wr2, br2, ln_g, ln_b, Wout, bout, fg, fb,
                       Wcst, bcst, Wcl, bcl, Cpre, (float*)d_out, B);
}

// Round 15
// 60.554 us; speedup vs baseline: 1.2101x; 1.0286x over previous
//
#include <hip/hip_runtime.h>

#define D 8
#define NE 4
#define NS 3
#define NI 5
#define LN_EPS 1e-5f

// wlds layout: per-stage blocks of 144 floats (576B, 16B-aligned):
//   +0   W1   (64, natural [d][k])
//   +64  W2T  (32, transposed [d][e])
//   +96  C    (32, n-paired [nn][d][2])
//   +128 B1   (8)
//   +136 B2   (4)
//   +140 pad  (4)
// then Wproj (NS*512) at 432, LN (16) at 1968.
#define STAGE_STRIDE 144
#define SOFF_W1  0
#define SOFF_W2T 64
#define SOFF_C   96
#define SOFF_B1  128
#define SOFF_B2  136
#define OFF_WP   432
#define OFF_LN   1968
#define WLDS_SIZE 1984

typedef float f2 __attribute__((ext_vector_type(2)));

__device__ __forceinline__ f2 fma2(f2 a, f2 b, f2 c) { return __builtin_elementwise_fma(a, b, c); }
__device__ __forceinline__ f2 max2(f2 a, f2 b) { return __builtin_elementwise_max(a, b); }
__device__ __forceinline__ f2 bc(float s) { return (f2){s, s}; }

// ---------------------------------------------------------------------------
// Setup kernel: C in n-PAIRED layout: C[s*32 + ((n>>1)*8 + d)*2 + (n&1)]
// ---------------------------------------------------------------------------
__global__ void precompute_C_kernel(const float* __restrict__ Bmat,
                                    const float* __restrict__ Wproj,
                                    const float* __restrict__ bproj,
                                    float* __restrict__ C) {
    int idx = threadIdx.x;
    if (idx >= NS * NE * D) return;
    int s = idx / (NE * D);
    int rem = idx % (NE * D);
    int n = rem / D;
    int d = rem % D;
    const float* bm = Bmat + ((size_t)s * NE + n) * 64;
    const float* wp = Wproj + ((size_t)s * D + d) * 64;
    float acc = bproj[s * D + d];
    #pragma unroll
    for (int k = 0; k < 64; ++k) acc += bm[k] * wp[k];
    C[s * 32 + ((n >> 1) * 8 + d) * 2 + (n & 1)] = acc;
}

__device__ __forceinline__ float fast_tanh(float x) {
    float e = __expf(2.f * x);
    return 1.f - 2.f * __builtin_amdgcn_rcpf(e + 1.f);
}

__device__ __forceinline__ float4 ld4(const float* p) {
    return *reinterpret_cast<const float4*>(p);
}

// ---------------------------------------------------------------------------
// Main kernel: ONE thread per row, f2 packing over expert pairs, t[8][8] in
// registers as exact f32 (R14 structure — session best). R15 diet:
//  (a) per-stage LDS blocks -> ONE gated pointer per iteration; all weight
//      reads are compile-time immediate offsets from it (kills ~34 address
//      v_adds/iter and 4 pointer regs);
//  (b) b1a/b2a register arrays GONE (-12 regs): b1[d] read per-d as scalar
//      broadcast, b2 as 4 transient scalars. Peak live ~119 < 128 -> the
//      ~11-dword/thread loop spill seen in R14 (WRITE 15.4MB vs 9.7 ideal)
//      should vanish.
// Opaque-zero LICM gate kept (R7-proven; memory clobber de-SROAs, R6). t is
// NOT gated (must stay register-resident).
// ---------------------------------------------------------------------------
__global__ __launch_bounds__(256, 2) void whisp_kernel(
    const float* __restrict__ cl, const float* __restrict__ cd,
    const float* __restrict__ re_log, const float* __restrict__ mach,
    const float* __restrict__ alpha, const float* __restrict__ u,
    const float* __restrict__ We, const float* __restrict__ be,
    const float* __restrict__ Wproj,
    const float* __restrict__ Wr1, const float* __restrict__ br1,
    const float* __restrict__ Wr2, const float* __restrict__ br2,
    const float* __restrict__ ln_g, const float* __restrict__ ln_b,
    const float* __restrict__ Wout, const float* __restrict__ bout,
    const float* __restrict__ fg, const float* __restrict__ fb,
    const float* __restrict__ Wcst, const float* __restrict__ bcst,
    const float* __restrict__ Wcl, const float* __restrict__ bcl,
    const float* __restrict__ Cpre,
    float* __restrict__ out, int B)
{
    __shared__ __align__(16) float wlds[WLDS_SIZE];   // 7936 B
    __shared__ __align__(16) float4 ubuf[2 * 256];    // 8192 B (per-thread uu)
    __shared__ float souts[256 * 19];                 // 19456 B

    const int tid = threadIdx.x;
    const int row0 = blockIdx.x * 256 + tid;
    const bool active = (row0 < B);
    const int row = active ? row0 : (B - 1);

    // ---- stage hot-loop weights into per-stage LDS blocks ----
    for (int i = tid; i < NS * 64; i += 256) {         // W1 natural
        int s = i / 64, j = i % 64;
        wlds[s * STAGE_STRIDE + SOFF_W1 + j] = Wr1[i];
    }
    for (int i = tid; i < NS * 32; i += 256) {         // W2 -> [d][e]
        int s = i / 32, j = i % 32, d = j / 4, e = j % 4;
        wlds[s * STAGE_STRIDE + SOFF_W2T + j] = Wr2[s * 32 + e * 8 + d];
    }
    for (int i = tid; i < NS * 32; i += 256) {         // C (already n-paired)
        int s = i / 32, j = i % 32;
        wlds[s * STAGE_STRIDE + SOFF_C + j] = Cpre[i];
    }
    for (int i = tid; i < NS * 8; i += 256) {          // B1
        int s = i / 8, j = i % 8;
        wlds[s * STAGE_STRIDE + SOFF_B1 + j] = br1[i];
    }
    for (int i = tid; i < NS * 4; i += 256) {          // B2
        int s = i / 4, j = i % 4;
        wlds[s * STAGE_STRIDE + SOFF_B2 + j] = br2[i];
    }
    for (int i = tid; i < 1536; i += 256) wlds[OFF_WP + i] = Wproj[i];
    for (int i = tid; i < 8; i += 256) { wlds[OFF_LN + i] = ln_g[i]; wlds[OFF_LN + 8 + i] = ln_b[i]; }

    // ---- per-row inputs; uu stashed in per-thread LDS (frees 8 regs) ----
    {
        const float4* up = reinterpret_cast<const float4*>(u + (size_t)row * D);
        ubuf[tid]       = up[0];
        ubuf[256 + tid] = up[1];
    }
    float xs[NE] = { cl[row], cd[row], re_log[row], mach[row] };
    float al = alpha[row];

    // ---- embedding -> E2[nn][d] = (E[2nn][d], E[2nn+1][d]) ----
    f2 E2[2][D];
    #pragma unroll
    for (int nn = 0; nn < 2; ++nn) {
        #pragma unroll
        for (int d = 0; d < D; ++d) {
            int na = 2 * nn, nb = 2 * nn + 1;
            float pa = We[na * 16 + d * 2] * xs[na] + We[na * 16 + d * 2 + 1] * al + be[na * D + d];
            float pb = We[nb * 16 + d * 2] * xs[nb] + We[nb * 16 + d * 2 + 1] * al + be[nb * D + d];
            E2[nn][d] = (f2){ fast_tanh(pa), fast_tanh(pb) };
        }
    }

    __syncthreads();   // wlds + ubuf ready

    int zero = 0;      // opaque 0: blocks LICM of broadcast weight loads

    // ---- outer stages ----
    #pragma unroll 1
    for (int s = 0; s < NS; ++s) {
        const float* stage_base = wlds + s * STAGE_STRIDE;

        // t[d][i] = sum_j u[j]*Wp[d][i*8+j] -> REGISTERS (f32, exact).
        float t[D][D];
        {
            float4 uq0 = ubuf[tid], uq1 = ubuf[256 + tid];
            f2 uu2[4] = { {uq0.x,uq0.y}, {uq0.z,uq0.w}, {uq1.x,uq1.y}, {uq1.z,uq1.w} };
            const float* Wp = wlds + OFF_WP + s * 512;
            #pragma unroll
            for (int d = 0; d < D; ++d) {
                #pragma unroll
                for (int i = 0; i < D; ++i) {
                    float4 wa = ld4(Wp + d * 64 + i * 8);
                    float4 wb = ld4(Wp + d * 64 + i * 8 + 4);
                    f2 acc = uu2[0] * (f2){wa.x, wa.y};
                    acc = fma2(uu2[1], (f2){wa.z, wa.w}, acc);
                    acc = fma2(uu2[2], (f2){wb.x, wb.y}, acc);
                    acc = fma2(uu2[3], (f2){wb.z, wb.w}, acc);
                    t[d][i] = acc.x + acc.y;
                }
            }
        }

        #pragma unroll 1
        for (int it = 0; it < NI; ++it) {
            // ONE gated base; all weight reads are imm offsets off it
            asm volatile("" : "+v"(zero));
            const float* sb = stage_base + zero;

            // H init from n-paired C (broadcast, imm offsets)
            f2 H2[2][D];
            #pragma unroll
            for (int nn = 0; nn < 2; ++nn) {
                #pragma unroll
                for (int dp = 0; dp < 4; ++dp) {
                    float4 cq = ld4(sb + SOFF_C + nn * 16 + dp * 4);
                    H2[nn][2 * dp]     = (f2){cq.x, cq.y};
                    H2[nn][2 * dp + 1] = (f2){cq.z, cq.w};
                }
            }
            // H2[nn][d] += sum_i E2[nn][i] * t[d][i]  (t from registers)
            #pragma unroll
            for (int d = 0; d < D; ++d) {
                #pragma unroll
                for (int nn = 0; nn < 2; ++nn) {
                    f2 acc = H2[nn][d];
                    acc = fma2(E2[nn][0], bc(t[d][0]), acc);
                    acc = fma2(E2[nn][1], bc(t[d][1]), acc);
                    acc = fma2(E2[nn][2], bc(t[d][2]), acc);
                    acc = fma2(E2[nn][3], bc(t[d][3]), acc);
                    acc = fma2(E2[nn][4], bc(t[d][4]), acc);
                    acc = fma2(E2[nn][5], bc(t[d][5]), acc);
                    acc = fma2(E2[nn][6], bc(t[d][6]), acc);
                    acc = fma2(E2[nn][7], bc(t[d][7]), acc);
                    H2[nn][d] = acc;
                }
            }

            // lg init from B2 (4 transient scalar broadcasts)
            f2 lg2[2][NE];
            {
                float b20 = sb[SOFF_B2 + 0], b21 = sb[SOFF_B2 + 1];
                float b22 = sb[SOFF_B2 + 2], b23 = sb[SOFF_B2 + 3];
                #pragma unroll
                for (int nn = 0; nn < 2; ++nn) {
                    lg2[nn][0] = bc(b20); lg2[nn][1] = bc(b21);
                    lg2[nn][2] = bc(b22); lg2[nn][3] = bc(b23);
                }
            }

            // fused routing: per d compute r2 then accumulate into lg
            #pragma unroll
            for (int d = 0; d < D; ++d) {
                float4 wa = ld4(sb + SOFF_W1 + d * 8);
                float4 wb = ld4(sb + SOFF_W1 + d * 8 + 4);
                float4 w2 = ld4(sb + SOFF_W2T + d * 4);
                float b1d = sb[SOFF_B1 + d];          // per-d scalar broadcast
                #pragma unroll
                for (int nn = 0; nn < 2; ++nn) {
                    f2 acc = bc(b1d);
                    acc = fma2(H2[nn][0], bc(wa.x), acc);
                    acc = fma2(H2[nn][1], bc(wa.y), acc);
                    acc = fma2(H2[nn][2], bc(wa.z), acc);
                    acc = fma2(H2[nn][3], bc(wa.w), acc);
                    acc = fma2(H2[nn][4], bc(wb.x), acc);
                    acc = fma2(H2[nn][5], bc(wb.y), acc);
                    acc = fma2(H2[nn][6], bc(wb.z), acc);
                    acc = fma2(H2[nn][7], bc(wb.w), acc);
                    f2 r2 = max2(acc, bc(0.f));
                    lg2[nn][0] = fma2(r2, bc(w2.x), lg2[nn][0]);
                    lg2[nn][1] = fma2(r2, bc(w2.y), lg2[nn][1]);
                    lg2[nn][2] = fma2(r2, bc(w2.z), lg2[nn][2]);
                    lg2[nn][3] = fma2(r2, bc(w2.w), lg2[nn][3]);
                }
            }

            // packed softmax over e (per n; n's in f2 lanes)
            f2 sm2[2][NE];
            #pragma unroll
            for (int nn = 0; nn < 2; ++nn) {
                f2 m2 = max2(max2(lg2[nn][0], lg2[nn][1]), max2(lg2[nn][2], lg2[nn][3]));
                f2 ee[NE];
                #pragma unroll
                for (int e = 0; e < NE; ++e) {
                    f2 tt = lg2[nn][e] - m2;
                    ee[e] = (f2){ __expf(tt.x), __expf(tt.y) };
                }
                f2 s2 = (ee[0] + ee[1]) + (ee[2] + ee[3]);
                f2 inv2 = (f2){ __builtin_amdgcn_rcpf(s2.x), __builtin_amdgcn_rcpf(s2.y) };
                #pragma unroll
                for (int e = 0; e < NE; ++e) sm2[nn][e] = ee[e] * inv2;
            }

            // E2[nn][d] += sum_e sm2[nn][e] * H[e][d]
            #pragma unroll
            for (int d = 0; d < D; ++d) {
                #pragma unroll
                for (int nn = 0; nn < 2; ++nn) {
                    f2 acc = E2[nn][d];
                    acc = fma2(sm2[nn][0], bc(H2[0][d].x), acc);
                    acc = fma2(sm2[nn][1], bc(H2[0][d].y), acc);
                    acc = fma2(sm2[nn][2], bc(H2[1][d].x), acc);
                    acc = fma2(sm2[nn][3], bc(H2[1][d].y), acc);
                    E2[nn][d] = acc;
                }
            }
        }

        // post-stage LayerNorm (params from LDS; packed math)
        float lngv[8], lnbv[8];
        {
            float4 g0 = ld4(wlds + OFF_LN),     g1 = ld4(wlds + OFF_LN + 4);
            float4 b0 = ld4(wlds + OFF_LN + 8), b1 = ld4(wlds + OFF_LN + 12);
            lngv[0]=g0.x; lngv[1]=g0.y; lngv[2]=g0.z; lngv[3]=g0.w;
            lngv[4]=g1.x; lngv[5]=g1.y; lngv[6]=g1.z; lngv[7]=g1.w;
            lnbv[0]=b0.x; lnbv[1]=b0.y; lnbv[2]=b0.z; lnbv[3]=b0.w;
            lnbv[4]=b1.x; lnbv[5]=b1.y; lnbv[6]=b1.z; lnbv[7]=b1.w;
        }
        #pragma unroll
        for (int nn = 0; nn < 2; ++nn) {
            f2 s2 = (E2[nn][0] + E2[nn][1]) + (E2[nn][2] + E2[nn][3]);
            s2 = s2 + (E2[nn][4] + E2[nn][5]) + (E2[nn][6] + E2[nn][7]);
            f2 m2 = s2 * bc(0.125f);
            f2 v2 = bc(0.f);
            #pragma unroll
            for (int d = 0; d < D; ++d) { f2 c = E2[nn][d] - m2; v2 = fma2(c, c, v2); }
            v2 = v2 * bc(0.125f);
            f2 inv2 = (f2){ __builtin_amdgcn_rsqf(v2.x + LN_EPS),
                            __builtin_amdgcn_rsqf(v2.y + LN_EPS) };
            #pragma unroll
            for (int d = 0; d < D; ++d)
                E2[nn][d] = fma2((E2[nn][d] - m2) * inv2, bc(lngv[d]), bc(lnbv[d]));
        }
    }

    // ---- final mixing (one-time global weights; scalar epilogue) ----
    float lgf[NE];
    #pragma unroll
    for (int e = 0; e < NE; ++e) {
        float a0 = bout[e], a1 = 0.f;
        #pragma unroll
        for (int d = 0; d < D; ++d) {
            a0 = fmaf(E2[0][d].x, Wout[e * 32 + 0 * D + d], a0);
            a1 = fmaf(E2[0][d].y, Wout[e * 32 + 1 * D + d], a1);
            a0 = fmaf(E2[1][d].x, Wout[e * 32 + 2 * D + d], a0);
            a1 = fmaf(E2[1][d].y, Wout[e * 32 + 3 * D + d], a1);
        }
        lgf[e] = a0 + a1;
    }
    float mx = fmaxf(fmaxf(lgf[0], lgf[1]), fmaxf(lgf[2], lgf[3]));
    float w0 = __expf(lgf[0] - mx), w1 = __expf(lgf[1] - mx);
    float w2 = __expf(lgf[2] - mx), w3 = __expf(lgf[3] - mx);
    float winv = __builtin_amdgcn_rcpf((w0 + w1) + (w2 + w3));
    w0 *= winv; w1 *= winv; w2 *= winv; w3 *= winv;

    float z[D];
    #pragma unroll
    for (int d = 0; d < D; ++d) {
        float a0 = w0 * E2[0][d].x;
        float a1 = w1 * E2[0][d].y;
        a0 = fmaf(w2, E2[1][d].x, a0);
        a1 = fmaf(w3, E2[1][d].y, a1);
        z[d] = a0 + a1;
    }
    float zm = 0.f;
    #pragma unroll
    for (int d = 0; d < D; ++d) zm += z[d];
    zm *= (1.f / D);
    float zv = 0.f;
    #pragma unroll
    for (int d = 0; d < D; ++d) { float c = z[d] - zm; zv = fmaf(c, c, zv); }
    zv *= (1.f / D);
    float zinv = __builtin_amdgcn_rsqf(zv + LN_EPS);
    #pragma unroll
    for (int d = 0; d < D; ++d)
        z[d] = (z[d] - zm) * zinv * fg[d] + fb[d];

    // heads
    float zout[19];
    #pragma unroll
    for (int k = 0; k < 18; ++k) {
        float a0 = bcst[k], a1 = 0.f;
        #pragma unroll
        for (int d = 0; d < D; d += 2) {
            a0 = fmaf(z[d],     Wcst[k * D + d],     a0);
            a1 = fmaf(z[d + 1], Wcst[k * D + d + 1], a1);
        }
        zout[k] = a0 + a1;
    }
    {
        float a0 = bcl[0], a1 = 0.f;
        #pragma unroll
        for (int d = 0; d < D; d += 2) {
            a0 = fmaf(z[d],     Wcl[d],     a0);
            a1 = fmaf(z[d + 1], Wcl[d + 1], a1);
        }
        zout[18] = a0 + a1;
    }

    // stage via LDS for coalesced stores
    if (active) {
        #pragma unroll
        for (int k = 0; k < 19; ++k) souts[tid * 19 + k] = zout[k];
    }
    __syncthreads();

    const int base = blockIdx.x * 256;
    int nrows = B - base;
    if (nrows > 256) nrows = 256;
    if (nrows > 0) {
        const int cnt = nrows * 19;
        for (int i = tid; i < cnt; i += 256)
            out[(size_t)base * 19 + i] = souts[i];
    }
}

extern "C" void kernel_launch(void* const* d_in, const int* in_sizes, int n_in,
                              void* d_out, int out_size, void* d_ws, size_t ws_size,
                              hipStream_t stream) {
    const float* cl     = (const float*)d_in[0];
    const float* cd     = (const float*)d_in[1];
    const float* re_log = (const float*)d_in[2];
    const float* mach   = (const float*)d_in[3];
    const float* alpha  = (const float*)d_in[4];
    const float* u      = (const float*)d_in[5];
    const float* We     = (const float*)d_in[6];
    const float* be     = (const float*)d_in[7];
    const float* Bmat   = (const float*)d_in[8];
    const float* Wproj  = (const float*)d_in[9];
    const float* bproj  = (const float*)d_in[10];
    const float* Wr1    = (const float*)d_in[11];
    const float* br1    = (const float*)d_in[12];
    const float* Wr2    = (const float*)d_in[13];
    const float* br2    = (const float*)d_in[14];
    const float* ln_g   = (const float*)d_in[15];
    const float* ln_b   = (const float*)d_in[16];
    const float* Wout   = (const float*)d_in[17];
    const float* bout   = (const float*)d_in[18];
    const float* fg     = (const float*)d_in[19];
    const float* fb     = (const float*)d_in[20];
    const float* Wcst   = (const float*)d_in[21];
    const float* bcst   = (const float*)d_in[22];
    const float* Wcl    = (const float*)d_in[23];
    const float* bcl    = (const float*)d_in[24];

    float* Cpre = (float*)d_ws;   // 96 floats (n-paired layout)
    const int B = in_sizes[0];

    hipLaunchKernelGGL(precompute_C_kernel, dim3(1), dim3(128), 0, stream,
                       Bmat, Wproj, bproj, Cpre);

    const int blocks = (B + 255) / 256;
    hipLaunchKernelGGL(whisp_kernel, dim3(blocks), dim3(256), 0, stream,
                       cl, cd, re_log, mach, alpha, u, We, be, Wproj,
                       Wr1, br1, Wr2, br2, ln_g, ln_b, Wout, bout, fg, fb,
                       Wcst, bcst, Wcl, bcl, Cpre, (float*)d_out, B);
}